// Round 13
// baseline (27.430 us; speedup 1.0000x reference)
//
#include <hip/hip_runtime.h>

#define NUM_EMBEDDINGS 50000
#define EMBEDDING_DIM  1024
#define N_CENTROIDS    256
#define N_BLOCKS       128    // EMBEDDING_DIM / 8
#define N_TOKENS       16384  // BATCH * SEQ
#define IDS_PER_BLOCK  16     // K1: 50000 = 3125 * 16 exactly
#define TOK_PER_BLOCK  8      // K2: 16384 = 2048 * 8 exactly

typedef float f32x4 __attribute__((ext_vector_type(4)));

// ---------- K1: transpose+narrow assignments -> codes8 [id][128] uint8 ------
// 3125 blocks x 16 ids. Each block reads 128 FULL 64B lines (16 ids x 4B,
// 16-id-aligned -> every fetched byte used; total 400K line requests vs the
// 2M random 4B requests of the blk-major gather). Repack via byte LDS tile,
// row stride 17 (17 coprime 32 -> write-phase lane reads hit 32 distinct
// banks). Output: 128B row per id, fully coalesced uchar4 writes. Plain
// (allocating) stores: codes8 wants to be L2/L3-resident for K2.
__global__ __launch_bounds__(256) void transpose_codes16_kernel(
    const int* __restrict__ assign,          // [128][50000]
    unsigned char* __restrict__ codes8)      // [50000][128]
{
    __shared__ unsigned char tile8[N_BLOCKS][IDS_PER_BLOCK + 1];  // stride 17

    const int t   = threadIdx.x;
    const int id0 = blockIdx.x * IDS_PER_BLOCK;

    // Read: linear 0..511 -> blk = linear>>2, col4 = linear&3 (int4 = 4 ids).
    // Per wave: 16 blk-rows x 64B contiguous — full-line utilization.
    #pragma unroll
    for (int k = 0; k < 2; ++k) {
        const int linear = t + 256 * k;
        const int blk    = linear >> 2;
        const int col4   = linear & 3;
        const int4 v = *reinterpret_cast<const int4*>(
            &assign[(size_t)blk * NUM_EMBEDDINGS + id0 + col4 * 4]);
        tile8[blk][col4 * 4 + 0] = (unsigned char)v.x;
        tile8[blk][col4 * 4 + 1] = (unsigned char)v.y;
        tile8[blk][col4 * 4 + 2] = (unsigned char)v.z;
        tile8[blk][col4 * 4 + 3] = (unsigned char)v.w;
    }
    __syncthreads();

    // Write: linear -> id_l = linear>>5, c4 = linear&31 (uchar4 column).
    // Row per id = 128 B contiguous across 32 lanes.
    #pragma unroll
    for (int k = 0; k < 2; ++k) {
        const int linear = t + 256 * k;
        const int id_l   = linear >> 5;
        const int c4     = linear & 31;
        const unsigned int b0 = tile8[4 * c4 + 0][id_l];
        const unsigned int b1 = tile8[4 * c4 + 1][id_l];
        const unsigned int b2 = tile8[4 * c4 + 2][id_l];
        const unsigned int b3 = tile8[4 * c4 + 3][id_l];
        reinterpret_cast<unsigned int*>(codes8)[(size_t)(id0 + id_l) * 32 + c4] =
            b0 | (b1 << 8) | (b2 << 16) | (b3 << 24);
    }
}

// ---------- K2: gather with coalesced code rows + nt stores ------------------
// 2048 blocks (8/CU) x 8 tokens. Group g (32 lanes) loads token g's 128 B
// code row coalesced (2 line requests/token; 32K total). Centroids in
// stride-9 LDS (random-code reads spread over all banks). Stores: 8 nt
// f32x4 per thread, block output = 32 KB contiguous.
__global__ __launch_bounds__(256) void pq_gather_rows_kernel(
    const float* __restrict__ centroids,          // [256][8]
    const unsigned char* __restrict__ codes8,     // [50000][128]
    const int* __restrict__ input_ids,            // [16384]
    float* __restrict__ out)                      // [16384][1024]
{
    __shared__ float        c_lds[N_CENTROIDS * 9];        // stride-9 padded
    __shared__ int          ids_lds[TOK_PER_BLOCK];
    __shared__ unsigned int cw[TOK_PER_BLOCK][33];         // code row words, pad

    const int t  = threadIdx.x;
    const int TB = blockIdx.x * TOK_PER_BLOCK;

    // stage centroids: coalesced f32x4 reads -> stride-9 LDS
    {
        const f32x4* __restrict__ cg4 = reinterpret_cast<const f32x4*>(centroids);
        #pragma unroll
        for (int k = 0; k < 2; ++k) {
            const int i = t + 256 * k;            // float4 index 0..511
            const f32x4 v = cg4[i];
            float* dst = &c_lds[(i >> 1) * 9 + (i & 1) * 4];
            dst[0] = v.x; dst[1] = v.y; dst[2] = v.z; dst[3] = v.w;
        }
    }
    if (t < TOK_PER_BLOCK)
        ids_lds[t] = input_ids[TB + t];
    __syncthreads();

    const int g    = t >> 5;    // token group 0..7
    const int lane = t & 31;

    // code row: 32 lanes x 4B = 128 B coalesced (2 L2 line requests)
    cw[g][lane] = reinterpret_cast<const unsigned int*>(codes8)[(size_t)ids_lds[g] * 32 + lane];
    __syncthreads();

    // stores: token g, f4 = lane + 32k  (wave = 2 x 512 B contiguous segments)
    const int half = lane & 1;
    f32x4* __restrict__ o4 = reinterpret_cast<f32x4*>(out) +
                             (size_t)(TB + g) * (EMBEDDING_DIM / 4);
    #pragma unroll
    for (int k = 0; k < 8; ++k) {
        const int f4   = lane + 32 * k;
        const int code = (cw[g][(lane >> 3) + 4 * k] >> (8 * ((lane >> 1) & 3))) & 0xFF;
        const float* __restrict__ cr = &c_lds[code * 9 + half * 4];
        f32x4 v;
        v.x = cr[0]; v.y = cr[1]; v.z = cr[2]; v.w = cr[3];
        __builtin_nontemporal_store(v, o4 + f4);
    }
}

// ---------- Fallback (R5 kernel, proven 19.8 us) if ws too small -------------
__global__ __launch_bounds__(256) void pq_embed_xcd_nt_kernel(
    const float* __restrict__ centroids,
    const int*   __restrict__ assignments,
    const int*   __restrict__ input_ids,
    float*       __restrict__ out)
{
    const int part  = blockIdx.x & 7;
    const int group = blockIdx.x >> 3;
    const int tid   = threadIdx.x;
    const int tgrp  = tid >> 5;
    const int lane  = tid & 31;

    const int token = group * 8 + tgrp;
    const int id    = input_ids[token];
    const int blk   = part * 16 + (lane >> 1);
    const int half  = lane & 1;

    const int code = assignments[(size_t)blk * NUM_EMBEDDINGS + id];
    const f32x4 v  = reinterpret_cast<const f32x4*>(centroids)[(code << 1) + half];

    f32x4* dst = reinterpret_cast<f32x4*>(out) +
                 (size_t)token * (EMBEDDING_DIM / 4) + part * 32 + lane;
    __builtin_nontemporal_store(v, dst);
}

extern "C" void kernel_launch(void* const* d_in, const int* in_sizes, int n_in,
                              void* d_out, int out_size, void* d_ws, size_t ws_size,
                              hipStream_t stream) {
    const float* centroids   = (const float*)d_in[0];
    const int*   assignments = (const int*)d_in[1];
    const int*   input_ids   = (const int*)d_in[2];
    float*       out         = (float*)d_out;

    const size_t ws_needed = (size_t)NUM_EMBEDDINGS * N_BLOCKS;  // 6.4 MB
    if (ws_size >= ws_needed) {
        unsigned char* codes8 = (unsigned char*)d_ws;
        transpose_codes16_kernel<<<NUM_EMBEDDINGS / IDS_PER_BLOCK, 256, 0, stream>>>(
            assignments, codes8);
        pq_gather_rows_kernel<<<N_TOKENS / TOK_PER_BLOCK, 256, 0, stream>>>(
            centroids, codes8, input_ids, out);
    } else {
        pq_embed_xcd_nt_kernel<<<N_TOKENS, 256, 0, stream>>>(
            centroids, assignments, input_ids, out);
    }
}